// Round 2
// baseline (2667.508 us; speedup 1.0000x reference)
//
#include <hip/hip_runtime.h>

#define BB 64
#define TT 1024
#define DD 256
#define HH 256

typedef float4 f4;
#define LD4(p) (*(const float4*)(p))

// tanh(x) = 1 - 2/(e^{2x}+1); saturates correctly for large |x|.
__device__ __forceinline__ float fast_tanh(float x) {
    float e = __expf(2.0f * x);
    return 1.0f - 2.0f / (e + 1.0f);
}

#define FMA4(acc, wv, xv)                 \
    acc = fmaf((wv).x, (xv).x, acc);      \
    acc = fmaf((wv).y, (xv).y, acc);      \
    acc = fmaf((wv).z, (xv).z, acc);      \
    acc = fmaf((wv).w, (xv).w, acc)

#define LOAD8(v0,v1,v2,v3,v4,v5,v6,v7, p)                                 \
    v0 = LD4((p)+0);  v1 = LD4((p)+4);  v2 = LD4((p)+8);  v3 = LD4((p)+12); \
    v4 = LD4((p)+16); v5 = LD4((p)+20); v6 = LD4((p)+24); v7 = LD4((p)+28)

// 8 float4 pairs -> 32 FMAs spread over 4 accumulator chains
#define DOT8(wa,wb,wc,wd,we,wf,wg,wh, xa,xb,xc,xd,xe,xf,xg,xh)            \
    FMA4(a0,wa,xa); FMA4(a1,wb,xb); FMA4(a2,wc,xc); FMA4(a3,wd,xd);       \
    FMA4(a0,we,xe); FMA4(a1,wf,xf); FMA4(a2,wg,xg); FMA4(a3,wh,xh)

// ---------------------------------------------------------------------------
// Phase 1: xp[b][t][j] = sum_d x[b][t][d] * W_ih[j][d] + b_ih[j]
// Grid: 512 WGs = B(64) x tslice(4) x jhalf(2), 512 threads.
// Thread (j, c=tid&3) holds W_ih[j][64c..64c+63] in 16 NAMED float4 regs
// (named scalars, not an array -> cannot be demoted to scratch).
// Row processed in two 8xfloat4 chunks to bound live registers (~110 VGPR).
// ---------------------------------------------------------------------------
__global__ __launch_bounds__(512, 4) void xproj_kernel(
    const float* __restrict__ x, const float* __restrict__ W_ih,
    const float* __restrict__ b_ih, float* __restrict__ xp)
{
    const int tid = threadIdx.x;
    const int c = tid & 3;                       // k-chunk 0..3
    const int j = ((blockIdx.x & 1) * 128) + (tid >> 2);
    const int t0 = ((blockIdx.x >> 1) & 3) * 256;
    const int b = blockIdx.x >> 3;

    const float* wp = W_ih + j * DD + c * 64;
    f4 w0,w1,w2,w3,w4,w5,w6,w7,w8,w9,w10,w11,w12,w13,w14,w15;
    LOAD8(w0,w1,w2,w3,w4,w5,w6,w7, wp);
    LOAD8(w8,w9,w10,w11,w12,w13,w14,w15, wp + 32);
    const float bias = b_ih[j];

    const float* xrow = x + (size_t)b * TT * DD + (size_t)t0 * DD + c * 64;
    float* xpo = xp + (size_t)b * TT * HH + (size_t)t0 * HH + j;

    for (int tt = 0; tt < 256; ++tt) {
        const float* xr = xrow + tt * DD;
        float a0 = 0.0f, a1 = 0.0f, a2 = 0.0f, a3 = 0.0f;
        {
            f4 x0,x1,x2,x3,x4,x5,x6,x7;
            LOAD8(x0,x1,x2,x3,x4,x5,x6,x7, xr);
            DOT8(w0,w1,w2,w3,w4,w5,w6,w7, x0,x1,x2,x3,x4,x5,x6,x7);
        }
        {
            f4 x0,x1,x2,x3,x4,x5,x6,x7;
            LOAD8(x0,x1,x2,x3,x4,x5,x6,x7, xr + 32);
            DOT8(w8,w9,w10,w11,w12,w13,w14,w15, x0,x1,x2,x3,x4,x5,x6,x7);
        }
        float acc = (a0 + a1) + (a2 + a3);
        acc += __shfl_xor(acc, 1);
        acc += __shfl_xor(acc, 2);
        if (c == 0) xpo[tt * HH] = acc + bias;
    }
}

// ---------------------------------------------------------------------------
// Phase 2: sequential recurrence, one WG per batch element (64 WGs, 1024 thr).
// Weights in 16 named float4 regs. h in LDS, double-buffered; chunk c at word
// offset c*68 (pad 4) -> the 4-distinct-address ds_read_b128 is conflict-free.
// io[] holds x_proj on entry, overwritten in place with h.
// ---------------------------------------------------------------------------
__global__ __launch_bounds__(1024) void rnn_kernel(
    const float* __restrict__ W_hh, const float* __restrict__ b_hh,
    float* __restrict__ io)
{
    const int tid = threadIdx.x;
    const int j = tid >> 2;   // 0..255 output unit
    const int c = tid & 3;    // 0..3 k-chunk
    const int b = blockIdx.x;

    __shared__ float hbuf[2][4 * 68];   // [buf][chunk*68 + pos]

    const float* wp = W_hh + j * HH + c * 64;
    f4 w0,w1,w2,w3,w4,w5,w6,w7,w8,w9,w10,w11,w12,w13,w14,w15;
    LOAD8(w0,w1,w2,w3,w4,w5,w6,w7, wp);
    LOAD8(w8,w9,w10,w11,w12,w13,w14,w15, wp + 32);
    const float bias = b_hh[j];

    if (tid < 272) hbuf[0][tid] = 0.0f;   // h_0 = 0
    __syncthreads();

    float* base = io + (size_t)b * TT * HH + j;

    // prefetch xp[0], xp[1]
    float xp0 = base[0];
    float xp1 = base[HH];

    int p = 0;
    for (int t = 0; t < TT; ++t) {
        // issue prefetch for xp[t+2] (lands during the dot phase)
        const int tn = (t + 2 < TT) ? (t + 2) : (TT - 1);
        const float xpn = base[(size_t)tn * HH];

        const float* hc = &hbuf[p][c * 68];
        float a0 = 0.0f, a1 = 0.0f, a2 = 0.0f, a3 = 0.0f;
        {
            f4 h0,h1,h2,h3,h4,h5,h6,h7;
            LOAD8(h0,h1,h2,h3,h4,h5,h6,h7, hc);
            DOT8(w0,w1,w2,w3,w4,w5,w6,w7, h0,h1,h2,h3,h4,h5,h6,h7);
        }
        {
            f4 h0,h1,h2,h3,h4,h5,h6,h7;
            LOAD8(h0,h1,h2,h3,h4,h5,h6,h7, hc + 32);
            DOT8(w8,w9,w10,w11,w12,w13,w14,w15, h0,h1,h2,h3,h4,h5,h6,h7);
        }
        float acc = (a0 + a1) + (a2 + a3);
        // combine the 4 k-chunks in-wave
        acc += __shfl_xor(acc, 1);
        acc += __shfl_xor(acc, 2);

        const float hn = fast_tanh(acc + xp0 + bias);
        if (c == 0) {
            hbuf[1 - p][((j >> 6) * 68) + (j & 63)] = hn;  // h for next step
            base[(size_t)t * HH] = hn;                      // output
        }
        xp0 = xp1;
        xp1 = xpn;
        p ^= 1;
        __syncthreads();
    }
}

extern "C" void kernel_launch(void* const* d_in, const int* in_sizes, int n_in,
                              void* d_out, int out_size, void* d_ws, size_t ws_size,
                              hipStream_t stream) {
    const float* x    = (const float*)d_in[0];
    const float* W_ih = (const float*)d_in[1];
    const float* W_hh = (const float*)d_in[2];
    const float* b_ih = (const float*)d_in[3];
    const float* b_hh = (const float*)d_in[4];
    float* out = (float*)d_out;

    // Phase 1: x_proj into d_out (aliased scratch; overwritten by phase 2).
    xproj_kernel<<<dim3(BB * 4 * 2), dim3(512), 0, stream>>>(x, W_ih, b_ih, out);
    // Phase 2: sequential recurrence, in-place on d_out.
    rnn_kernel<<<dim3(BB), dim3(1024), 0, stream>>>(W_hh, b_hh, out);
}

// Round 4
// 1092.195 us; speedup vs baseline: 2.4423x; 2.4423x over previous
//
#include <hip/hip_runtime.h>

#define BB 64
#define TT 1024
#define DD 256
#define HH 256

// Native clang vector type — required for asm "v" constraints (HIP's float4
// is a struct and would be rejected by inline asm).
typedef float vf4 __attribute__((ext_vector_type(4)));
#define LD4(p) (*(const vf4*)(p))

// tanh(x) = 1 - 2/(e^{2x}+1); saturates correctly for large |x|.
__device__ __forceinline__ float fast_tanh(float x) {
    float e = __expf(2.0f * x);
    return 1.0f - 2.0f / (e + 1.0f);
}

// NOTE: macro params must NOT be named x/y/z/w — the preprocessor would
// substitute the component-accessor tokens too ((w).w -> (w1).w1).

// rr += ss * bb (scalar-broadcast FMA onto a 4-vector)
#define FMR(rr, bb, ss)                   \
    rr.x = fmaf((ss), (bb).x, rr.x);      \
    rr.y = fmaf((ss), (bb).y, rr.y);      \
    rr.z = fmaf((ss), (bb).z, rr.z);      \
    rr.w = fmaf((ss), (bb).w, rr.w)

// dot4 accumulate: aa += dot(ww, hh)
#define FMR4(aa, ww, hh)                  \
    aa = fmaf((ww).x, (hh).x, aa);        \
    aa = fmaf((ww).y, (hh).y, aa);        \
    aa = fmaf((ww).z, (hh).z, aa);        \
    aa = fmaf((ww).w, (hh).w, aa)

// ---------------------------------------------------------------------------
// Phase 1: xp = x[65536x256] * W_ih^T[256x256] + b_ih  (standard tiled GEMM)
// Tile 128x128, BK=32, 256 threads, 8x8 micro-tile (split 4+4 in both dims).
// As/Bs stored k-major with +4 pad: a-reads are 4-address broadcasts,
// b-reads are 2-way (free). waves_per_eu(4,4) -> 128-VGPR budget.
// ---------------------------------------------------------------------------
#define BKb 32       // K tile
#define LDP 132      // padded row stride (floats); row base 528 B, 16B-aligned

__global__ __attribute__((amdgpu_flat_work_group_size(256, 256),
                          amdgpu_waves_per_eu(4, 4)))
void xproj_kernel(const float* __restrict__ x, const float* __restrict__ W_ih,
                  const float* __restrict__ b_ih, float* __restrict__ xp)
{
    __shared__ float As[BKb][LDP];   // As[k][m]
    __shared__ float Bs[BKb][LDP];   // Bs[k][n]

    const int tid = threadIdx.x;
    const int nb = blockIdx.x & 1;        // 2 N-blocks
    const int mb = blockIdx.x >> 1;       // 512 M-blocks
    const int m0 = mb * 128;
    const int n0 = nb * 128;

    // staging: thread loads one float4 from each of 4 rows (A and B)
    const int sr = tid >> 3;              // 0..31
    const int sk = (tid & 7) * 4;         // 0,4,..,28

    // compute mapping: 16x16 threads, each 8x8 outputs (4+4 split)
    const int tx = tid & 15;
    const int ty = tid >> 4;
    const int ma = ty * 4, mh = 64 + ty * 4;
    const int na = tx * 4, nh = 64 + tx * 4;

    vf4 ra0 = 0, ra1 = 0, ra2 = 0, ra3 = 0, ra4 = 0, ra5 = 0, ra6 = 0, ra7 = 0;
    vf4 rb0 = 0, rb1 = 0, rb2 = 0, rb3 = 0, rb4 = 0, rb5 = 0, rb6 = 0, rb7 = 0;

    for (int k0 = 0; k0 < DD; k0 += BKb) {
        #pragma unroll
        for (int g = 0; g < 4; ++g) {
            const int r = sr + g * 32;
            const vf4 v = LD4(x + (size_t)(m0 + r) * DD + k0 + sk);
            As[sk + 0][r] = v.x; As[sk + 1][r] = v.y;
            As[sk + 2][r] = v.z; As[sk + 3][r] = v.w;
        }
        #pragma unroll
        for (int g = 0; g < 4; ++g) {
            const int n = sr + g * 32;
            const vf4 v = LD4(W_ih + (size_t)(n0 + n) * DD + k0 + sk);
            Bs[sk + 0][n] = v.x; Bs[sk + 1][n] = v.y;
            Bs[sk + 2][n] = v.z; Bs[sk + 3][n] = v.w;
        }
        __syncthreads();

        #pragma unroll
        for (int kk = 0; kk < BKb; ++kk) {
            const vf4 alo = LD4(&As[kk][ma]);
            const vf4 ahi = LD4(&As[kk][mh]);
            const vf4 bl  = LD4(&Bs[kk][na]);
            const vf4 bh  = LD4(&Bs[kk][nh]);
            FMR(ra0, bl, alo.x); FMR(rb0, bh, alo.x);
            FMR(ra1, bl, alo.y); FMR(rb1, bh, alo.y);
            FMR(ra2, bl, alo.z); FMR(rb2, bh, alo.z);
            FMR(ra3, bl, alo.w); FMR(rb3, bh, alo.w);
            FMR(ra4, bl, ahi.x); FMR(rb4, bh, ahi.x);
            FMR(ra5, bl, ahi.y); FMR(rb5, bh, ahi.y);
            FMR(ra6, bl, ahi.z); FMR(rb6, bh, ahi.z);
            FMR(ra7, bl, ahi.w); FMR(rb7, bh, ahi.w);
        }
        __syncthreads();
    }

    const vf4 bia = LD4(b_ih + n0 + na);
    const vf4 bib = LD4(b_ih + n0 + nh);

    #define STORE_ROW(m, rA, rB)                                   \
        {                                                          \
            float* outp = xp + (size_t)(m0 + (m)) * HH + n0;       \
            *(vf4*)(outp + na) = rA + bia;                         \
            *(vf4*)(outp + nh) = rB + bib;                         \
        }
    STORE_ROW(ma + 0, ra0, rb0); STORE_ROW(ma + 1, ra1, rb1);
    STORE_ROW(ma + 2, ra2, rb2); STORE_ROW(ma + 3, ra3, rb3);
    STORE_ROW(mh + 0, ra4, rb4); STORE_ROW(mh + 1, ra5, rb5);
    STORE_ROW(mh + 2, ra6, rb6); STORE_ROW(mh + 3, ra7, rb7);
    #undef STORE_ROW
}

// ---------------------------------------------------------------------------
// Phase 2: sequential recurrence, one WG per batch (64 WGs, 1024 threads).
// Thread (j = tid>>2, c = tid&3) holds W_hh[j][64c..64c+63] in 16 vf4 regs,
// pinned live every iteration by an asm barrier (defeats load-sinking/remat).
// waves_per_eu(4,4): 16 waves = 1 WG/CU -> 128-VGPR budget (need ~115).
// h in LDS double buffer; chunk c at word c*68 -> vf4 reads are 4-address
// broadcasts on distinct banks (conflict-free).
// ---------------------------------------------------------------------------
__global__ __attribute__((amdgpu_flat_work_group_size(1024, 1024),
                          amdgpu_waves_per_eu(4, 4)))
void rnn_kernel(const float* __restrict__ W_hh, const float* __restrict__ b_hh,
                float* __restrict__ io)
{
    const int tid = threadIdx.x;
    const int j = tid >> 2;   // 0..255 output unit
    const int c = tid & 3;    // 0..3 k-chunk
    const int b = blockIdx.x;

    __shared__ float hbuf[2][4 * 68];   // [buf][chunk*68 + pos]

    const float* wp = W_hh + j * HH + c * 64;
    vf4 w0  = LD4(wp +  0), w1  = LD4(wp +  4), w2  = LD4(wp +  8), w3  = LD4(wp + 12);
    vf4 w4  = LD4(wp + 16), w5  = LD4(wp + 20), w6  = LD4(wp + 24), w7  = LD4(wp + 28);
    vf4 w8  = LD4(wp + 32), w9  = LD4(wp + 36), w10 = LD4(wp + 40), w11 = LD4(wp + 44);
    vf4 w12 = LD4(wp + 48), w13 = LD4(wp + 52), w14 = LD4(wp + 56), w15 = LD4(wp + 60);
    const float bias = b_hh[j];

    if (tid < 272) hbuf[0][tid] = 0.0f;   // h_0 = 0
    __syncthreads();

    float* base = io + (size_t)b * TT * HH + j;

    float xp0 = base[0];        // prefetch xp[0], xp[1]
    float xp1 = base[HH];

    int p = 0;
    for (int t = 0; t < TT; ++t) {
        // Pin all 16 weight quads in VGPRs this iteration (no remat/sink).
        asm volatile("" : "+v"(w0), "+v"(w1), "+v"(w2), "+v"(w3),
                          "+v"(w4), "+v"(w5), "+v"(w6), "+v"(w7),
                          "+v"(w8), "+v"(w9), "+v"(w10), "+v"(w11),
                          "+v"(w12), "+v"(w13), "+v"(w14), "+v"(w15));

        // prefetch xp[t+2] (lands during the dot phase)
        const int tn = (t + 2 < TT) ? (t + 2) : (TT - 1);
        const float xpn = base[(size_t)tn * HH];

        const float* hc = &hbuf[p][c * 68];
        float a0 = 0.0f, a1 = 0.0f, a2 = 0.0f, a3 = 0.0f;
        {
            const vf4 h0 = LD4(hc + 0),  h1 = LD4(hc + 4),
                      h2 = LD4(hc + 8),  h3 = LD4(hc + 12),
                      h4 = LD4(hc + 16), h5 = LD4(hc + 20),
                      h6 = LD4(hc + 24), h7 = LD4(hc + 28);
            FMR4(a0, w0, h0); FMR4(a1, w1, h1); FMR4(a2, w2, h2); FMR4(a3, w3, h3);
            FMR4(a0, w4, h4); FMR4(a1, w5, h5); FMR4(a2, w6, h6); FMR4(a3, w7, h7);
        }
        {
            const vf4 h0 = LD4(hc + 32), h1 = LD4(hc + 36),
                      h2 = LD4(hc + 40), h3 = LD4(hc + 44),
                      h4 = LD4(hc + 48), h5 = LD4(hc + 52),
                      h6 = LD4(hc + 56), h7 = LD4(hc + 60);
            FMR4(a0, w8, h0);  FMR4(a1, w9, h1);  FMR4(a2, w10, h2); FMR4(a3, w11, h3);
            FMR4(a0, w12, h4); FMR4(a1, w13, h5); FMR4(a2, w14, h6); FMR4(a3, w15, h7);
        }
        float acc = (a0 + a1) + (a2 + a3);
        acc += __shfl_xor(acc, 1);
        acc += __shfl_xor(acc, 2);

        const float hn = fast_tanh(acc + xp0 + bias);
        if (c == 0) {
            hbuf[1 - p][((j >> 6) * 68) + (j & 63)] = hn;  // h for next step
            base[(size_t)t * HH] = hn;                      // output
        }
        xp0 = xp1;
        xp1 = xpn;
        p ^= 1;
        __syncthreads();
    }
}

extern "C" void kernel_launch(void* const* d_in, const int* in_sizes, int n_in,
                              void* d_out, int out_size, void* d_ws, size_t ws_size,
                              hipStream_t stream) {
    const float* x    = (const float*)d_in[0];
    const float* W_ih = (const float*)d_in[1];
    const float* W_hh = (const float*)d_in[2];
    const float* b_ih = (const float*)d_in[3];
    const float* b_hh = (const float*)d_in[4];
    float* out = (float*)d_out;

    // Phase 1: x_proj into d_out (aliased scratch; overwritten by phase 2).
    xproj_kernel<<<dim3(512 * 2), dim3(256), 0, stream>>>(x, W_ih, b_ih, out);
    // Phase 2: sequential recurrence, in-place on d_out.
    rnn_kernel<<<dim3(BB), dim3(1024), 0, stream>>>(W_hh, b_hh, out);
}

// Round 5
// 927.119 us; speedup vs baseline: 2.8772x; 1.1781x over previous
//
#include <hip/hip_runtime.h>

#define BB 64
#define TT 1024
#define DD 256
#define HH 256

typedef float vf4 __attribute__((ext_vector_type(4)));
typedef float vf2 __attribute__((ext_vector_type(2)));
struct alignas(16) v2x2 { vf2 lo, hi; };   // one 16-B load, two pk-operands

#define LD4(p) (*(const vf4*)(p))
#define LDW(p) (*(const v2x2*)(p))

// tanh(x) = 1 - 2/(e^{2x}+1); saturates correctly for large |x|.
__device__ __forceinline__ float fast_tanh(float x) {
    float e = __expf(2.0f * x);
    return 1.0f - 2.0f / (e + 1.0f);
}

// float2 FMA: selects v_pk_fma_f32 on gfx950 (exact fp32, 2x rate).
#define PKFMA(acc, aa, bb) acc = __builtin_elementwise_fma((aa), (bb), (acc))

// dst = src + dpp_shuffle(src). VALU-pipe cross-lane (no LDS traffic).
// CTRL: 0xB1 quad_perm xor1, 0x4E quad_perm xor2, 0x124 row_ror:4, 0x128 row_ror:8.
#define DPPADD(dst, src, CTRL) {                                                   \
    int _di = __builtin_amdgcn_update_dpp(0, __float_as_int(src), CTRL, 0xF, 0xF, true); \
    dst = (src) + __int_as_float(_di); }

// NOTE: macro params must NOT be named x/y/z/w (component-accessor capture).
#define FMR(rr, bb, ss)                   \
    rr.x = fmaf((ss), (bb).x, rr.x);      \
    rr.y = fmaf((ss), (bb).y, rr.y);      \
    rr.z = fmaf((ss), (bb).z, rr.z);      \
    rr.w = fmaf((ss), (bb).w, rr.w)

// ---------------------------------------------------------------------------
// Phase 1 (unchanged from R4, ~160 us): xp = x * W_ih^T + b_ih, tiled GEMM.
// ---------------------------------------------------------------------------
#define BKb 32
#define LDP 132

__global__ __attribute__((amdgpu_flat_work_group_size(256, 256),
                          amdgpu_waves_per_eu(4, 4)))
void xproj_kernel(const float* __restrict__ x, const float* __restrict__ W_ih,
                  const float* __restrict__ b_ih, float* __restrict__ xp)
{
    __shared__ float As[BKb][LDP];
    __shared__ float Bs[BKb][LDP];

    const int tid = threadIdx.x;
    const int nb = blockIdx.x & 1;
    const int mb = blockIdx.x >> 1;
    const int m0 = mb * 128;
    const int n0 = nb * 128;

    const int sr = tid >> 3;
    const int sk = (tid & 7) * 4;

    const int tx = tid & 15;
    const int ty = tid >> 4;
    const int ma = ty * 4, mh = 64 + ty * 4;
    const int na = tx * 4, nh = 64 + tx * 4;

    vf4 ra0 = 0, ra1 = 0, ra2 = 0, ra3 = 0, ra4 = 0, ra5 = 0, ra6 = 0, ra7 = 0;
    vf4 rb0 = 0, rb1 = 0, rb2 = 0, rb3 = 0, rb4 = 0, rb5 = 0, rb6 = 0, rb7 = 0;

    for (int k0 = 0; k0 < DD; k0 += BKb) {
        #pragma unroll
        for (int g = 0; g < 4; ++g) {
            const int r = sr + g * 32;
            const vf4 v = LD4(x + (size_t)(m0 + r) * DD + k0 + sk);
            As[sk + 0][r] = v.x; As[sk + 1][r] = v.y;
            As[sk + 2][r] = v.z; As[sk + 3][r] = v.w;
        }
        #pragma unroll
        for (int g = 0; g < 4; ++g) {
            const int n = sr + g * 32;
            const vf4 v = LD4(W_ih + (size_t)(n0 + n) * DD + k0 + sk);
            Bs[sk + 0][n] = v.x; Bs[sk + 1][n] = v.y;
            Bs[sk + 2][n] = v.z; Bs[sk + 3][n] = v.w;
        }
        __syncthreads();

        #pragma unroll
        for (int kk = 0; kk < BKb; ++kk) {
            const vf4 alo = LD4(&As[kk][ma]);
            const vf4 ahi = LD4(&As[kk][mh]);
            const vf4 bl  = LD4(&Bs[kk][na]);
            const vf4 bh  = LD4(&Bs[kk][nh]);
            FMR(ra0, bl, alo.x); FMR(rb0, bh, alo.x);
            FMR(ra1, bl, alo.y); FMR(rb1, bh, alo.y);
            FMR(ra2, bl, alo.z); FMR(rb2, bh, alo.z);
            FMR(ra3, bl, alo.w); FMR(rb3, bh, alo.w);
            FMR(ra4, bl, ahi.x); FMR(rb4, bh, ahi.x);
            FMR(ra5, bl, ahi.y); FMR(rb5, bh, ahi.y);
            FMR(ra6, bl, ahi.z); FMR(rb6, bh, ahi.z);
            FMR(ra7, bl, ahi.w); FMR(rb7, bh, ahi.w);
        }
        __syncthreads();
    }

    const vf4 bia = LD4(b_ih + n0 + na);
    const vf4 bib = LD4(b_ih + n0 + nh);

    #define STORE_ROW(m, rA, rB)                                   \
        {                                                          \
            float* outp = xp + (size_t)(m0 + (m)) * HH + n0;       \
            *(vf4*)(outp + na) = rA + bia;                         \
            *(vf4*)(outp + nh) = rB + bib;                         \
        }
    STORE_ROW(ma + 0, ra0, rb0); STORE_ROW(ma + 1, ra1, rb1);
    STORE_ROW(ma + 2, ra2, rb2); STORE_ROW(ma + 3, ra3, rb3);
    STORE_ROW(mh + 0, ra4, rb4); STORE_ROW(mh + 1, ra5, rb5);
    STORE_ROW(mh + 2, ra6, rb6); STORE_ROW(mh + 3, ra7, rb7);
    #undef STORE_ROW
}

// ---------------------------------------------------------------------------
// Phase 2: recurrence, one WG per batch (64 WGs, 1024 threads).
// Re-tiled Jt=4 x Kt=16: thread (jg=tid>>4, c=tid&15) computes outputs
// j0..j0+3 over k-chunk c -> only 4 ds_read_b128 of h per thread per step
// (64 wave-instrs/step/CU vs 256 in R4 -> fixes the LDS-issue bottleneck).
// Reduction over the 16 c-lanes entirely via DPP adds (VALU pipe).
// h chunk c at word c*20 (+4 pad): 16 b128 addresses cover all 32 banks.
// ---------------------------------------------------------------------------
__global__ __attribute__((amdgpu_flat_work_group_size(1024, 1024),
                          amdgpu_waves_per_eu(4, 4)))
void rnn_kernel(const float* __restrict__ W_hh, const float* __restrict__ b_hh,
                float* __restrict__ io)
{
    const int tid = threadIdx.x;
    const int jg = tid >> 4;          // 0..63: group of 4 outputs
    const int c  = tid & 15;          // 0..15: k-chunk (16 floats)
    const int j0 = jg * 4;
    const int jmine = j0 + (c & 3);   // the output this lane finalizes
    const int b = blockIdx.x;

    __shared__ float hbuf[2][16 * 20];   // h[k] at word (k>>4)*20 + (k&15)

    // Weights: rows j0..j0+3, cols c*16..c*16+15 (16 x v2x2 = 64 VGPRs).
    const float* wr0 = W_hh + (size_t)(j0 + 0) * HH + c * 16;
    const float* wr1 = W_hh + (size_t)(j0 + 1) * HH + c * 16;
    const float* wr2 = W_hh + (size_t)(j0 + 2) * HH + c * 16;
    const float* wr3 = W_hh + (size_t)(j0 + 3) * HH + c * 16;
    v2x2 w00 = LDW(wr0 + 0), w01 = LDW(wr0 + 4), w02 = LDW(wr0 + 8), w03 = LDW(wr0 + 12);
    v2x2 w10 = LDW(wr1 + 0), w11 = LDW(wr1 + 4), w12 = LDW(wr1 + 8), w13 = LDW(wr1 + 12);
    v2x2 w20 = LDW(wr2 + 0), w21 = LDW(wr2 + 4), w22 = LDW(wr2 + 8), w23 = LDW(wr2 + 12);
    v2x2 w30 = LDW(wr3 + 0), w31 = LDW(wr3 + 4), w32 = LDW(wr3 + 8), w33 = LDW(wr3 + 12);
    const float bias = b_hh[jmine];

    if (tid < 320) hbuf[0][tid] = 0.0f;   // h_0 = 0 (pads incl., never read)
    __syncthreads();

    const float* pj = io + (size_t)b * TT * HH + jmine;   // xp reads
    float*       po = io + (size_t)b * TT * HH + jmine;   // h writes
    const int haddr = ((jmine >> 4) * 20) + (jmine & 15); // LDS slot for jmine

    float xp0 = pj[0];
    float xp1 = pj[HH];

    int p = 0;
    for (int t = 0; t < TT; ++t) {
        // Pin weights live in arch VGPRs each iteration (defeat sinking/remat).
        asm volatile("" : "+v"(w00.lo), "+v"(w00.hi), "+v"(w01.lo), "+v"(w01.hi),
                          "+v"(w02.lo), "+v"(w02.hi), "+v"(w03.lo), "+v"(w03.hi),
                          "+v"(w10.lo), "+v"(w10.hi), "+v"(w11.lo), "+v"(w11.hi),
                          "+v"(w12.lo), "+v"(w12.hi), "+v"(w13.lo), "+v"(w13.hi));
        asm volatile("" : "+v"(w20.lo), "+v"(w20.hi), "+v"(w21.lo), "+v"(w21.hi),
                          "+v"(w22.lo), "+v"(w22.hi), "+v"(w23.lo), "+v"(w23.hi),
                          "+v"(w30.lo), "+v"(w30.hi), "+v"(w31.lo), "+v"(w31.hi),
                          "+v"(w32.lo), "+v"(w32.hi), "+v"(w33.lo), "+v"(w33.hi));

        const int tn = (t + 2 < TT) ? (t + 2) : (TT - 1);
        const float xpn = pj[(size_t)tn * HH];

        const float* hc = &hbuf[p][c * 20];
        const v2x2 h0 = LDW(hc + 0), h1 = LDW(hc + 4),
                   h2 = LDW(hc + 8), h3 = LDW(hc + 12);

        vf2 a0 = {0.f, 0.f}, a1 = {0.f, 0.f}, a2 = {0.f, 0.f}, a3 = {0.f, 0.f};
        PKFMA(a0, w00.lo, h0.lo); PKFMA(a1, w10.lo, h0.lo);
        PKFMA(a2, w20.lo, h0.lo); PKFMA(a3, w30.lo, h0.lo);
        PKFMA(a0, w00.hi, h0.hi); PKFMA(a1, w10.hi, h0.hi);
        PKFMA(a2, w20.hi, h0.hi); PKFMA(a3, w30.hi, h0.hi);
        PKFMA(a0, w01.lo, h1.lo); PKFMA(a1, w11.lo, h1.lo);
        PKFMA(a2, w21.lo, h1.lo); PKFMA(a3, w31.lo, h1.lo);
        PKFMA(a0, w01.hi, h1.hi); PKFMA(a1, w11.hi, h1.hi);
        PKFMA(a2, w21.hi, h1.hi); PKFMA(a3, w31.hi, h1.hi);
        PKFMA(a0, w02.lo, h2.lo); PKFMA(a1, w12.lo, h2.lo);
        PKFMA(a2, w22.lo, h2.lo); PKFMA(a3, w32.lo, h2.lo);
        PKFMA(a0, w02.hi, h2.hi); PKFMA(a1, w12.hi, h2.hi);
        PKFMA(a2, w22.hi, h2.hi); PKFMA(a3, w32.hi, h2.hi);
        PKFMA(a0, w03.lo, h3.lo); PKFMA(a1, w13.lo, h3.lo);
        PKFMA(a2, w23.lo, h3.lo); PKFMA(a3, w33.lo, h3.lo);
        PKFMA(a0, w03.hi, h3.hi); PKFMA(a1, w13.hi, h3.hi);
        PKFMA(a2, w23.hi, h3.hi); PKFMA(a3, w33.hi, h3.hi);

        const float s0 = a0.x + a0.y, s1 = a1.x + a1.y,
                    s2 = a2.x + a2.y, s3 = a3.x + a3.y;

        // Reduce over the 16 c-lanes (DPP, VALU pipe). After xor1/xor2 with
        // value-splitting, lane holds row r = c&3 summed over its quad; ror:4
        // and ror:8 map quad q->q+1/q+2 preserving r -> full sum.
        float t0, t1, t2, t3, b0v, b1v, u0, u1, vfin;
        DPPADD(t0, s0, 0xB1); DPPADD(t1, s1, 0xB1);
        DPPADD(t2, s2, 0xB1); DPPADD(t3, s3, 0xB1);
        b0v = (c & 1) ? t1 : t0;
        b1v = (c & 1) ? t3 : t2;
        DPPADD(u0, b0v, 0x4E); DPPADD(u1, b1v, 0x4E);
        vfin = (c & 2) ? u1 : u0;
        DPPADD(vfin, vfin, 0x124);
        DPPADD(vfin, vfin, 0x128);

        const float hn = fast_tanh(vfin + xp0 + bias);
        if (c < 4) {
            hbuf[1 - p][haddr] = hn;           // h for next step
            po[(size_t)t * HH] = hn;           // output (overwrites xp[t])
        }
        xp0 = xp1;
        xp1 = xpn;
        p ^= 1;
        __syncthreads();
    }
}

extern "C" void kernel_launch(void* const* d_in, const int* in_sizes, int n_in,
                              void* d_out, int out_size, void* d_ws, size_t ws_size,
                              hipStream_t stream) {
    const float* x    = (const float*)d_in[0];
    const float* W_ih = (const float*)d_in[1];
    const float* W_hh = (const float*)d_in[2];
    const float* b_ih = (const float*)d_in[3];
    const float* b_hh = (const float*)d_in[4];
    float* out = (float*)d_out;

    xproj_kernel<<<dim3(512 * 2), dim3(256), 0, stream>>>(x, W_ih, b_ih, out);
    rnn_kernel<<<dim3(BB), dim3(1024), 0, stream>>>(W_hh, b_hh, out);
}

// Round 6
// 916.289 us; speedup vs baseline: 2.9112x; 1.0118x over previous
//
#include <hip/hip_runtime.h>

#define BB 64
#define TT 1024
#define DD 256
#define HH 256

typedef float vf4 __attribute__((ext_vector_type(4)));
typedef float vf2 __attribute__((ext_vector_type(2)));
struct alignas(16) v2x2 { vf2 lo, hi; };   // one 16-B load, two pk-operands

#define LD4(p) (*(const vf4*)(p))
#define LDW(p) (*(const v2x2*)(p))

// tanh(x) = 1 - 2/(e^{2x}+1); saturates correctly for large |x|.
__device__ __forceinline__ float fast_tanh(float x) {
    float e = __expf(2.0f * x);
    return 1.0f - 2.0f / (e + 1.0f);
}

// float2 FMA: selects v_pk_fma_f32 on gfx950 (exact fp32, 2x rate).
#define PKFMA(acc, aa, bb) acc = __builtin_elementwise_fma((aa), (bb), (acc))

// dst = src + dpp_shuffle(src). VALU-pipe cross-lane (no LDS traffic).
// CTRL: 0xB1 quad_perm xor1, 0x4E quad_perm xor2, 0x124 row_ror:4, 0x128 row_ror:8.
#define DPPADD(dst, src, CTRL) {                                                   \
    int _di = __builtin_amdgcn_update_dpp(0, __float_as_int(src), CTRL, 0xF, 0xF, true); \
    dst = (src) + __int_as_float(_di); }

// NOTE: macro params must NOT be named x/y/z/w (component-accessor capture).
#define FMR(rr, bb, ss)                   \
    rr.x = fmaf((ss), (bb).x, rr.x);      \
    rr.y = fmaf((ss), (bb).y, rr.y);      \
    rr.z = fmaf((ss), (bb).z, rr.z);      \
    rr.w = fmaf((ss), (bb).w, rr.w)

// ---------------------------------------------------------------------------
// Phase 1 (unchanged, ~170 us): xp = x * W_ih^T + b_ih, tiled GEMM.
// ---------------------------------------------------------------------------
#define BKb 32
#define LDP 132

__global__ __attribute__((amdgpu_flat_work_group_size(256, 256),
                          amdgpu_waves_per_eu(4, 4)))
void xproj_kernel(const float* __restrict__ x, const float* __restrict__ W_ih,
                  const float* __restrict__ b_ih, float* __restrict__ xp)
{
    __shared__ float As[BKb][LDP];
    __shared__ float Bs[BKb][LDP];

    const int tid = threadIdx.x;
    const int nb = blockIdx.x & 1;
    const int mb = blockIdx.x >> 1;
    const int m0 = mb * 128;
    const int n0 = nb * 128;

    const int sr = tid >> 3;
    const int sk = (tid & 7) * 4;

    const int tx = tid & 15;
    const int ty = tid >> 4;
    const int ma = ty * 4, mh = 64 + ty * 4;
    const int na = tx * 4, nh = 64 + tx * 4;

    vf4 ra0 = 0, ra1 = 0, ra2 = 0, ra3 = 0, ra4 = 0, ra5 = 0, ra6 = 0, ra7 = 0;
    vf4 rb0 = 0, rb1 = 0, rb2 = 0, rb3 = 0, rb4 = 0, rb5 = 0, rb6 = 0, rb7 = 0;

    for (int k0 = 0; k0 < DD; k0 += BKb) {
        #pragma unroll
        for (int g = 0; g < 4; ++g) {
            const int r = sr + g * 32;
            const vf4 v = LD4(x + (size_t)(m0 + r) * DD + k0 + sk);
            As[sk + 0][r] = v.x; As[sk + 1][r] = v.y;
            As[sk + 2][r] = v.z; As[sk + 3][r] = v.w;
        }
        #pragma unroll
        for (int g = 0; g < 4; ++g) {
            const int n = sr + g * 32;
            const vf4 v = LD4(W_ih + (size_t)(n0 + n) * DD + k0 + sk);
            Bs[sk + 0][n] = v.x; Bs[sk + 1][n] = v.y;
            Bs[sk + 2][n] = v.z; Bs[sk + 3][n] = v.w;
        }
        __syncthreads();

        #pragma unroll
        for (int kk = 0; kk < BKb; ++kk) {
            const vf4 alo = LD4(&As[kk][ma]);
            const vf4 ahi = LD4(&As[kk][mh]);
            const vf4 bl  = LD4(&Bs[kk][na]);
            const vf4 bh  = LD4(&Bs[kk][nh]);
            FMR(ra0, bl, alo.x); FMR(rb0, bh, alo.x);
            FMR(ra1, bl, alo.y); FMR(rb1, bh, alo.y);
            FMR(ra2, bl, alo.z); FMR(rb2, bh, alo.z);
            FMR(ra3, bl, alo.w); FMR(rb3, bh, alo.w);
            FMR(ra4, bl, ahi.x); FMR(rb4, bh, ahi.x);
            FMR(ra5, bl, ahi.y); FMR(rb5, bh, ahi.y);
            FMR(ra6, bl, ahi.z); FMR(rb6, bh, ahi.z);
            FMR(ra7, bl, ahi.w); FMR(rb7, bh, ahi.w);
        }
        __syncthreads();
    }

    const vf4 bia = LD4(b_ih + n0 + na);
    const vf4 bib = LD4(b_ih + n0 + nh);

    #define STORE_ROW(m, rA, rB)                                   \
        {                                                          \
            float* outp = xp + (size_t)(m0 + (m)) * HH + n0;       \
            *(vf4*)(outp + na) = rA + bia;                         \
            *(vf4*)(outp + nh) = rB + bib;                         \
        }
    STORE_ROW(ma + 0, ra0, rb0); STORE_ROW(ma + 1, ra1, rb1);
    STORE_ROW(ma + 2, ra2, rb2); STORE_ROW(ma + 3, ra3, rb3);
    STORE_ROW(mh + 0, ra4, rb4); STORE_ROW(mh + 1, ra5, rb5);
    STORE_ROW(mh + 2, ra6, rb6); STORE_ROW(mh + 3, ra7, rb7);
    #undef STORE_ROW
}

// ---------------------------------------------------------------------------
// Phase 2: recurrence, one WG per batch (64 WGs, 1024 threads).
// Same compute structure as R5 (Jt=4 x Kt=16, DPP reduction). ONE change:
// xp is read from a SEPARATE buffer (xpin) than the h output (hout) — breaks
// the store->load alias on `io` that serialized every step on global-memory
// round trips (R5: 1770 cyc/step with only ~300 cyc VALU+190 LDS accounted).
// ---------------------------------------------------------------------------
__global__ __attribute__((amdgpu_flat_work_group_size(1024, 1024),
                          amdgpu_waves_per_eu(4, 4)))
void rnn_kernel(const float* __restrict__ W_hh, const float* __restrict__ b_hh,
                const float* __restrict__ xpin, float* __restrict__ hout)
{
    const int tid = threadIdx.x;
    const int jg = tid >> 4;          // 0..63: group of 4 outputs
    const int c  = tid & 15;          // 0..15: k-chunk (16 floats)
    const int j0 = jg * 4;
    const int jmine = j0 + (c & 3);   // the output this lane finalizes
    const int b = blockIdx.x;

    __shared__ float hbuf[2][16 * 20];   // h[k] at word (k>>4)*20 + (k&15)

    const float* wr0 = W_hh + (size_t)(j0 + 0) * HH + c * 16;
    const float* wr1 = W_hh + (size_t)(j0 + 1) * HH + c * 16;
    const float* wr2 = W_hh + (size_t)(j0 + 2) * HH + c * 16;
    const float* wr3 = W_hh + (size_t)(j0 + 3) * HH + c * 16;
    v2x2 w00 = LDW(wr0 + 0), w01 = LDW(wr0 + 4), w02 = LDW(wr0 + 8), w03 = LDW(wr0 + 12);
    v2x2 w10 = LDW(wr1 + 0), w11 = LDW(wr1 + 4), w12 = LDW(wr1 + 8), w13 = LDW(wr1 + 12);
    v2x2 w20 = LDW(wr2 + 0), w21 = LDW(wr2 + 4), w22 = LDW(wr2 + 8), w23 = LDW(wr2 + 12);
    v2x2 w30 = LDW(wr3 + 0), w31 = LDW(wr3 + 4), w32 = LDW(wr3 + 8), w33 = LDW(wr3 + 12);
    const float bias = b_hh[jmine];

    if (tid < 320) hbuf[0][tid] = 0.0f;   // h_0 = 0 (pads incl., never read)
    __syncthreads();

    const float* pj = xpin + (size_t)b * TT * HH + jmine;   // xp reads
    float*       po = hout + (size_t)b * TT * HH + jmine;   // h writes
    const int haddr = ((jmine >> 4) * 20) + (jmine & 15);   // LDS slot for jmine

    float xp0 = pj[0];
    float xp1 = pj[HH];

    int p = 0;
    for (int t = 0; t < TT; ++t) {
        // Pin weights live each iteration (defeat sinking/remat).
        asm volatile("" : "+v"(w00.lo), "+v"(w00.hi), "+v"(w01.lo), "+v"(w01.hi),
                          "+v"(w02.lo), "+v"(w02.hi), "+v"(w03.lo), "+v"(w03.hi),
                          "+v"(w10.lo), "+v"(w10.hi), "+v"(w11.lo), "+v"(w11.hi),
                          "+v"(w12.lo), "+v"(w12.hi), "+v"(w13.lo), "+v"(w13.hi));
        asm volatile("" : "+v"(w20.lo), "+v"(w20.hi), "+v"(w21.lo), "+v"(w21.hi),
                          "+v"(w22.lo), "+v"(w22.hi), "+v"(w23.lo), "+v"(w23.hi),
                          "+v"(w30.lo), "+v"(w30.hi), "+v"(w31.lo), "+v"(w31.hi),
                          "+v"(w32.lo), "+v"(w32.hi), "+v"(w33.lo), "+v"(w33.hi));

        const int tn = (t + 2 < TT) ? (t + 2) : (TT - 1);
        const float xpn = pj[(size_t)tn * HH];

        const float* hc = &hbuf[p][c * 20];
        const v2x2 h0 = LDW(hc + 0), h1 = LDW(hc + 4),
                   h2 = LDW(hc + 8), h3 = LDW(hc + 12);

        vf2 a0 = {0.f, 0.f}, a1 = {0.f, 0.f}, a2 = {0.f, 0.f}, a3 = {0.f, 0.f};
        PKFMA(a0, w00.lo, h0.lo); PKFMA(a1, w10.lo, h0.lo);
        PKFMA(a2, w20.lo, h0.lo); PKFMA(a3, w30.lo, h0.lo);
        PKFMA(a0, w00.hi, h0.hi); PKFMA(a1, w10.hi, h0.hi);
        PKFMA(a2, w20.hi, h0.hi); PKFMA(a3, w30.hi, h0.hi);
        PKFMA(a0, w01.lo, h1.lo); PKFMA(a1, w11.lo, h1.lo);
        PKFMA(a2, w21.lo, h1.lo); PKFMA(a3, w31.lo, h1.lo);
        PKFMA(a0, w01.hi, h1.hi); PKFMA(a1, w11.hi, h1.hi);
        PKFMA(a2, w21.hi, h1.hi); PKFMA(a3, w31.hi, h1.hi);
        PKFMA(a0, w02.lo, h2.lo); PKFMA(a1, w12.lo, h2.lo);
        PKFMA(a2, w22.lo, h2.lo); PKFMA(a3, w32.lo, h2.lo);
        PKFMA(a0, w02.hi, h2.hi); PKFMA(a1, w12.hi, h2.hi);
        PKFMA(a2, w22.hi, h2.hi); PKFMA(a3, w32.hi, h2.hi);
        PKFMA(a0, w03.lo, h3.lo); PKFMA(a1, w13.lo, h3.lo);
        PKFMA(a2, w23.lo, h3.lo); PKFMA(a3, w33.lo, h3.lo);
        PKFMA(a0, w03.hi, h3.hi); PKFMA(a1, w13.hi, h3.hi);
        PKFMA(a2, w23.hi, h3.hi); PKFMA(a3, w33.hi, h3.hi);

        const float s0 = a0.x + a0.y, s1 = a1.x + a1.y,
                    s2 = a2.x + a2.y, s3 = a3.x + a3.y;

        float t0, t1, t2, t3, b0v, b1v, u0, u1, vfin;
        DPPADD(t0, s0, 0xB1); DPPADD(t1, s1, 0xB1);
        DPPADD(t2, s2, 0xB1); DPPADD(t3, s3, 0xB1);
        b0v = (c & 1) ? t1 : t0;
        b1v = (c & 1) ? t3 : t2;
        DPPADD(u0, b0v, 0x4E); DPPADD(u1, b1v, 0x4E);
        vfin = (c & 2) ? u1 : u0;
        DPPADD(vfin, vfin, 0x124);
        DPPADD(vfin, vfin, 0x128);

        const float hn = fast_tanh(vfin + xp0 + bias);
        if (c < 4) {
            hbuf[1 - p][haddr] = hn;           // h for next step
            po[(size_t)t * HH] = hn;           // output (separate buffer!)
        }
        xp0 = xp1;
        xp1 = xpn;
        p ^= 1;
        __syncthreads();
    }
}

extern "C" void kernel_launch(void* const* d_in, const int* in_sizes, int n_in,
                              void* d_out, int out_size, void* d_ws, size_t ws_size,
                              hipStream_t stream) {
    const float* x    = (const float*)d_in[0];
    const float* W_ih = (const float*)d_in[1];
    const float* W_hh = (const float*)d_in[2];
    const float* b_ih = (const float*)d_in[3];
    const float* b_hh = (const float*)d_in[4];
    float* out = (float*)d_out;

    const size_t xp_bytes = (size_t)BB * TT * HH * sizeof(float);   // 64 MiB
    float* xp = (ws_size >= xp_bytes) ? (float*)d_ws : out;   // de-aliased if ws fits

    xproj_kernel<<<dim3(512 * 2), dim3(256), 0, stream>>>(x, W_ih, b_ih, xp);
    rnn_kernel<<<dim3(BB), dim3(1024), 0, stream>>>(W_hh, b_hh, xp, out);
}